// Round 4
// baseline (334.387 us; speedup 1.0000x reference)
//
#include <hip/hip_runtime.h>
#include <math.h>

#define NN 10000
#define NE 160000
#define NB 4
#define NH 4
#define ND 256
#define NT (NN * 16)        // (n,b,h) triples
#define NM 40000            // GEMM rows (b*NN+n)

typedef _Float16 f16;
typedef _Float16 half8 __attribute__((ext_vector_type(8)));
typedef float f32x4 __attribute__((ext_vector_type(4)));

union H4 { uint2 u; f16 h[4]; };

__device__ __forceinline__ void gload_lds16(const void* g, void* l) {
  __builtin_amdgcn_global_load_lds((const __attribute__((address_space(1))) void*)g,
                                   (__attribute__((address_space(3))) void*)l, 16, 0, 0);
}

// ---------------- CSR build ----------------
__global__ __launch_bounds__(256) void k_deg(const int* __restrict__ dst, int* __restrict__ deg) {
  int e = blockIdx.x * 256 + threadIdx.x;
  if (e < NE) atomicAdd(&deg[dst[e]], 1);
}

__global__ __launch_bounds__(1024) void k_scan(const int* __restrict__ deg, int* __restrict__ offs) {
  __shared__ int tmp[1024];
  __shared__ int carry_s;
  if (threadIdx.x == 0) carry_s = 0;
  __syncthreads();
  for (int base = 0; base < NN; base += 1024) {
    int i = base + (int)threadIdx.x;
    int v = (i < NN) ? deg[i] : 0;
    int c0 = carry_s;
    tmp[threadIdx.x] = v;
    __syncthreads();
    for (int s = 1; s < 1024; s <<= 1) {
      int add = (threadIdx.x >= (unsigned)s) ? tmp[threadIdx.x - s] : 0;
      __syncthreads();
      tmp[threadIdx.x] += add;
      __syncthreads();
    }
    if (i < NN) offs[i] = c0 + tmp[threadIdx.x] - v;   // exclusive
    int tot = tmp[1023];
    __syncthreads();
    if (threadIdx.x == 0) carry_s = c0 + tot;
    __syncthreads();
  }
  if (threadIdx.x == 0) offs[NN] = carry_s;
}

__global__ __launch_bounds__(256) void k_scatter(const int* __restrict__ src, const int* __restrict__ dst,
                                                 const float* __restrict__ w, const int* __restrict__ offs,
                                                 int* __restrict__ cursor, int* __restrict__ csr_src,
                                                 float* __restrict__ csr_w) {
  int e = blockIdx.x * 256 + threadIdx.x;
  if (e < NE) {
    int d = dst[e];
    int slot = offs[d] + atomicAdd(&cursor[d], 1);
    csr_src[slot] = src[e];
    csr_w[slot] = w[e];
  }
}

// ---------------- converters ----------------
__global__ __launch_bounds__(256) void k_cvt_sol(const float* __restrict__ sol, f16* __restrict__ solh) {
  int i = blockIdx.x * 256 + threadIdx.x;
  int row = i >> 6, q = i & 63;
  int k = q << 2;
  const float* s = (k < 128) ? (sol + (size_t)row * 128 + k)
                             : (sol + (size_t)(NM + row) * 128 + (k - 128));
  float4 v = *(const float4*)s;
  H4 h;
  h.h[0] = (f16)v.x; h.h[1] = (f16)v.y; h.h[2] = (f16)v.z; h.h[3] = (f16)v.w;
  *(uint2*)(solh + (size_t)row * 256 + k) = h.u;
}

__global__ __launch_bounds__(256) void k_cvt4(const float* __restrict__ in, f16* __restrict__ out, int n4) {
  int i = blockIdx.x * 256 + threadIdx.x;
  if (i < n4) {
    float4 v = *(const float4*)(in + (size_t)i * 4);
    H4 h;
    h.h[0] = (f16)v.x; h.h[1] = (f16)v.y; h.h[2] = (f16)v.z; h.h[3] = (f16)v.w;
    *(uint2*)(out + (size_t)i * 4) = h.u;
  }
}

// ---------------- weight fusion ----------------
__global__ __launch_bounds__(256) void k_fuse_wh(const float* __restrict__ fc_w, const float* __restrict__ ofc_w,
                                                 f16* __restrict__ fwh) {
  int r = blockIdx.x;        // 0..255 = h*64+o
  int d = threadIdx.x;       // 0..255
  int h = r >> 6, o = r & 63;
  float acc = 0.f;
  for (int f = 0; f < 64; ++f)
    acc = fmaf(ofc_w[(o << 6) + f], fc_w[(((h << 6) + f) << 8) + d], acc);
  fwh[(r << 8) + d] = (f16)acc;
}

__global__ __launch_bounds__(256) void k_fuse_attn(const float* __restrict__ fc_w,
                                                   const float* __restrict__ al, const float* __restrict__ ar,
                                                   float* __restrict__ alf) {
  int r = blockIdx.x;        // 0..7
  int d = threadIdx.x;
  int h = r & 3;
  const float* a = (r < 4) ? al : ar;
  float acc = 0.f;
  for (int f = 0; f < 64; ++f)
    acc = fmaf(a[(h << 6) + f], fc_w[(((h << 6) + f) << 8) + d], acc);
  alf[(r << 8) + d] = acc;
}

// ---------------- MFMA fp16 GEMM ----------------
// PERM=0: out[ra][col] fp32/fp16 per OUTH. PERM=2: featW_t[(b*4+h)][n][o] fp16.
template<int PERM, int OUTH>
__global__ __launch_bounds__(256) void k_gemm_f16(
    const f16* __restrict__ A, int lda, int K,
    const f16* __restrict__ W,
    const float* __restrict__ bias,
    void* __restrict__ outp, int ldo)
{
  __shared__ __align__(16) f16 As[64 * 32];
  __shared__ __align__(16) f16 Bs[128 * 32];
  const int tid = threadIdx.x;
  const int lane = tid & 63;
  const int w = tid >> 6;
  const int wr = w >> 1, wc = w & 1;
  const int ra0 = blockIdx.x * 64;
  const int c0 = blockIdx.y * 128;
  const int l2 = lane >> 2;
  const int lk8 = (lane & 3) * 8;

  f32x4 acc[2][4];
#pragma unroll
  for (int mr = 0; mr < 2; ++mr)
#pragma unroll
    for (int nr = 0; nr < 4; ++nr) acc[mr][nr] = (f32x4)0.f;

  const int fr = lane & 15;
  const int fg = (lane >> 4) * 8;

  for (int k0 = 0; k0 < K; k0 += 32) {
    gload_lds16(A + (size_t)(ra0 + 16 * w + l2) * lda + k0 + lk8, As + w * 512);
    gload_lds16(W + (size_t)(c0 + 32 * w + l2) * K + k0 + lk8, Bs + w * 1024);
    gload_lds16(W + (size_t)(c0 + 32 * w + 16 + l2) * K + k0 + lk8, Bs + w * 1024 + 512);
    __syncthreads();

    half8 af[2], bf[4];
#pragma unroll
    for (int mr = 0; mr < 2; ++mr)
      af[mr] = *(const half8*)(As + (wr * 32 + mr * 16 + fr) * 32 + fg);
#pragma unroll
    for (int nr = 0; nr < 4; ++nr)
      bf[nr] = *(const half8*)(Bs + (wc * 64 + nr * 16 + fr) * 32 + fg);
#pragma unroll
    for (int mr = 0; mr < 2; ++mr)
#pragma unroll
      for (int nr = 0; nr < 4; ++nr)
        acc[mr][nr] = __builtin_amdgcn_mfma_f32_16x16x32_f16(af[mr], bf[nr], acc[mr][nr], 0, 0, 0);
    __syncthreads();
  }

  const int r0 = (lane >> 4) * 4;
#pragma unroll
  for (int nr = 0; nr < 4; ++nr) {
    int col = c0 + wc * 64 + nr * 16 + fr;
    float bv = bias ? bias[col] : 0.f;
    int h = col >> 6, o = col & 63;
#pragma unroll
    for (int mr = 0; mr < 2; ++mr) {
      f32x4 v = acc[mr][nr];
#pragma unroll
      for (int r = 0; r < 4; ++r) {
        int ra = ra0 + wr * 32 + mr * 16 + r0 + r;
        float val = v[r] + bv;
        if (PERM == 2) {
          int n = ra % NN, b = ra / NN;
          ((f16*)outp)[(((size_t)(b * 4 + h) * NN + n) << 6) + o] = (f16)val;
        } else if (OUTH) {
          ((f16*)outp)[(size_t)ra * ldo + col] = (f16)val;
        } else {
          ((float*)outp)[(size_t)ra * ldo + col] = val;
        }
      }
    }
  }
}

// ---------------- el/er (bh-major transposed out) ----------------
__global__ __launch_bounds__(256) void k_eler3h(
    const f16* __restrict__ xh, int lda,
    const float* __restrict__ alf, float* __restrict__ el_t, float* __restrict__ er_t)
{
  int wid = threadIdx.x >> 6, lane = threadIdx.x & 63;
  int ra = blockIdx.x * 4 + wid;        // b*NN+n
  int k0 = lane << 2;
  H4 hv;
  hv.u = *(const uint2*)(xh + (size_t)ra * lda + k0);
  float x0 = (float)hv.h[0], x1 = (float)hv.h[1], x2 = (float)hv.h[2], x3 = (float)hv.h[3];
  int n = ra % NN, b = ra / NN;
#pragma unroll
  for (int oi = 0; oi < 8; ++oi) {
    float4 av = *(const float4*)(alf + (oi << 8) + k0);
    float s = x0 * av.x + x1 * av.y + x2 * av.z + x3 * av.w;
#pragma unroll
    for (int k = 32; k; k >>= 1) s += __shfl_xor(s, k);
    if (lane == 0) {
      int h = oi & 3;
      size_t idx = (size_t)(b * 4 + h) * NN + n;
      if (oi < 4) el_t[idx] = s;
      else        er_t[idx] = s;
    }
  }
}

// ---------------- edge softmax + aggregate, bh-split, wave-per-node ----------------
// blockIdx.x = chunk*16 + bh  -> XCD = bid%8 = bh%8 (round-robin): per-XCD L2 holds
// 2 featW slices (2x1.28MB) + el/er slices. Wave w handles node chunk*4+w.
__global__ __launch_bounds__(256) void k_edge3(
    const f16* __restrict__ featW_t, const float* __restrict__ el_t, const float* __restrict__ er_t,
    const int* __restrict__ csr_src, const float* __restrict__ csr_w, const int* __restrict__ offs,
    const float* __restrict__ b2, f16* __restrict__ outh)
{
  __shared__ float2 as_[4][64];        // {alpha, bitcast(src)} per wave
  const int t = threadIdx.x;
  const int w = t >> 6, lane = t & 63;
  const int bh = blockIdx.x & 15;
  const int n = (blockIdx.x >> 4) * 4 + w;
  const int s0 = offs[n], s1 = offs[n + 1];
  const float erv = er_t[(size_t)bh * NN + n];
  const float* elp = el_t + (size_t)bh * NN;
  const f16* fW = featW_t + ((size_t)bh * NN << 6);

  float m = -INFINITY, srun = 0.f, acc = 0.f;
  for (int c0 = s0; c0 < s1; c0 += 64) {
    const int csz = min(64, s1 - c0);
    float sc = -INFINITY;
    int src = 0;
    if (lane < csz) {
      src = csr_src[c0 + lane];
      float x = elp[src] + erv;
      x = (x > 0.f) ? x : 0.1f * x;
      sc = x * csr_w[c0 + lane];
    }
    // wave max
    float mc = sc;
#pragma unroll
    for (int k = 32; k; k >>= 1) mc = fmaxf(mc, __shfl_xor(mc, k));
    float mn = fmaxf(m, mc);
    float alpha = (lane < csz) ? __expf(sc - mn) : 0.f;
    float ps = alpha;
#pragma unroll
    for (int k = 32; k; k >>= 1) ps += __shfl_xor(ps, k);
    float sl = (m == -INFINITY) ? 0.f : __expf(m - mn);
    srun = srun * sl + ps;
    m = mn;
    as_[w][lane] = make_float2(alpha, __int_as_float(src));
    acc *= sl;
    for (int e = 0; e < csz; ++e) {
      float2 p = as_[w][e];                       // ds_read_b64 broadcast
      int sn = __float_as_int(p.y);
      acc = fmaf(p.x, (float)fW[((size_t)sn << 6) + lane], acc);
    }
  }
  float invs = (s1 > s0) ? 1.f / srun : 0.f;
  float r = fmaxf(fmaf(acc, invs, b2[lane]), 0.f);
  const int b = bh >> 2, h = bh & 3;
  outh[(((size_t)b * NN + n) << 9) + (h << 6) + lane] = (f16)r;
}

// ---------------- launch ----------------
extern "C" void kernel_launch(void* const* d_in, const int* in_sizes, int n_in,
                              void* d_out, int out_size, void* d_ws, size_t ws_size,
                              hipStream_t stream) {
  const float* sol    = (const float*)d_in[0];
  const float* w      = (const float*)d_in[1];
  const float* fc_w   = (const float*)d_in[2];
  const float* attn_l = (const float*)d_in[3];
  const float* attn_r = (const float*)d_in[4];
  const float* ofc_w  = (const float*)d_in[5];
  const float* ofc_b  = (const float*)d_in[6];
  const float* mlp_w  = (const float*)d_in[7];
  const float* mlp_b  = (const float*)d_in[8];
  const int*   d_src  = (const int*)d_in[9];
  const int*   d_dst  = (const int*)d_in[10];
  float* out = (float*)d_out;

  char* p = (char*)d_ws;
  auto alloc = [&](size_t bytes) { char* r = p; p += (bytes + 255) & ~(size_t)255; return r; };
  f16*   solh    = (f16*)alloc((size_t)NM * 256 * 2);
  f16*   out01h  = (f16*)alloc((size_t)NM * 512 * 2);
  f16*   featWt  = (f16*)alloc((size_t)NT * 64 * 2);       // [16][NN][64]
  f16*   fwh     = (f16*)alloc((size_t)ND * ND * 2);
  f16*   mlph    = (f16*)alloc((size_t)ND * 512 * 2);
  float* el_t    = (float*)alloc((size_t)NT * 4);          // [16][NN]
  float* er_t    = (float*)alloc((size_t)NT * 4);
  float* alf     = (float*)alloc((size_t)8 * ND * 4);
  int*   deg     = (int*)alloc((size_t)(NN + 1) * 4);
  int*   offs    = (int*)alloc((size_t)(NN + 1) * 4);
  int*   cursor  = (int*)alloc((size_t)NN * 4);
  int*   csr_src = (int*)alloc((size_t)NE * 4);
  float* csr_w   = (float*)alloc((size_t)NE * 4);
  if ((size_t)(p - (char*)d_ws) > ws_size) return;

  hipMemsetAsync(deg, 0, (size_t)NN * 4, stream);
  hipMemsetAsync(cursor, 0, (size_t)NN * 4, stream);
  k_deg<<<NE / 256, 256, 0, stream>>>(d_dst, deg);
  k_scan<<<1, 1024, 0, stream>>>(deg, offs);
  k_scatter<<<NE / 256, 256, 0, stream>>>(d_src, d_dst, w, offs, cursor, csr_src, csr_w);

  k_cvt_sol<<<NM * 64 / 256, 256, 0, stream>>>(sol, solh);
  k_cvt4<<<(ND * 512 / 4 + 255) / 256, 256, 0, stream>>>(mlp_w, mlph, ND * 512 / 4);

  for (int l = 0; l < 2; ++l) {
    const float* fcl = fc_w + (size_t)l * ND * ND;
    k_fuse_wh<<<256, 256, 0, stream>>>(fcl, ofc_w + (size_t)l * 64 * 64, fwh);
    k_fuse_attn<<<8, 256, 0, stream>>>(fcl, attn_l + (size_t)l * NH * 64, attn_r + (size_t)l * NH * 64, alf);
    const f16* Ah = (l == 0) ? solh : out01h;
    int lda = (l == 0) ? 256 : 512;
    k_gemm_f16<2, 1><<<dim3(NM / 64, ND / 128), 256, 0, stream>>>(
        Ah, lda, 256, fwh, nullptr, featWt, 64);
    k_eler3h<<<NM / 4, 256, 0, stream>>>(Ah, lda, alf, el_t, er_t);
    k_edge3<<<(NN / 4) * 16, 256, 0, stream>>>(featWt, el_t, er_t, csr_src, csr_w, offs,
                                               ofc_b + (size_t)l * 64, out01h + (l == 0 ? 0 : 256));
  }

  k_gemm_f16<0, 0><<<dim3(NM / 64, ND / 128), 256, 0, stream>>>(
      out01h, 512, 512, mlph, mlp_b, out, 256);
}

// Round 5
// 328.355 us; speedup vs baseline: 1.0184x; 1.0184x over previous
//
#include <hip/hip_runtime.h>
#include <math.h>

#define NN 10000
#define NE 160000
#define NB 4
#define NH 4
#define ND 256
#define NT (NN * 16)        // (n,b,h) triples
#define NM 40000            // GEMM rows (b*NN+n)

typedef _Float16 f16;
typedef _Float16 half8 __attribute__((ext_vector_type(8)));
typedef float f32x4 __attribute__((ext_vector_type(4)));

union H4 { uint2 u; f16 h[4]; };

__device__ __forceinline__ void gload_lds16(const void* g, void* l) {
  __builtin_amdgcn_global_load_lds((const __attribute__((address_space(1))) void*)g,
                                   (__attribute__((address_space(3))) void*)l, 16, 0, 0);
}

// ---------------- CSR build ----------------
__global__ __launch_bounds__(256) void k_deg(const int* __restrict__ dst, int* __restrict__ deg) {
  int e = blockIdx.x * 256 + threadIdx.x;
  if (e < NE) atomicAdd(&deg[dst[e]], 1);
}

__global__ __launch_bounds__(1024) void k_scan(const int* __restrict__ deg, int* __restrict__ offs) {
  __shared__ int tmp[1024];
  __shared__ int carry_s;
  if (threadIdx.x == 0) carry_s = 0;
  __syncthreads();
  for (int base = 0; base < NN; base += 1024) {
    int i = base + (int)threadIdx.x;
    int v = (i < NN) ? deg[i] : 0;
    int c0 = carry_s;
    tmp[threadIdx.x] = v;
    __syncthreads();
    for (int s = 1; s < 1024; s <<= 1) {
      int add = (threadIdx.x >= (unsigned)s) ? tmp[threadIdx.x - s] : 0;
      __syncthreads();
      tmp[threadIdx.x] += add;
      __syncthreads();
    }
    if (i < NN) offs[i] = c0 + tmp[threadIdx.x] - v;   // exclusive
    int tot = tmp[1023];
    __syncthreads();
    if (threadIdx.x == 0) carry_s = c0 + tot;
    __syncthreads();
  }
  if (threadIdx.x == 0) offs[NN] = carry_s;
}

__global__ __launch_bounds__(256) void k_scatter(const int* __restrict__ src, const int* __restrict__ dst,
                                                 const float* __restrict__ w, const int* __restrict__ offs,
                                                 int* __restrict__ cursor, int* __restrict__ csr_src,
                                                 float* __restrict__ csr_w) {
  int e = blockIdx.x * 256 + threadIdx.x;
  if (e < NE) {
    int d = dst[e];
    int slot = offs[d] + atomicAdd(&cursor[d], 1);
    csr_src[slot] = src[e];
    csr_w[slot] = w[e];
  }
}

// ---------------- converters ----------------
__global__ __launch_bounds__(256) void k_cvt_sol(const float* __restrict__ sol, f16* __restrict__ solh) {
  int i = blockIdx.x * 256 + threadIdx.x;
  int row = i >> 6, q = i & 63;
  int k = q << 2;
  const float* s = (k < 128) ? (sol + (size_t)row * 128 + k)
                             : (sol + (size_t)(NM + row) * 128 + (k - 128));
  float4 v = *(const float4*)s;
  H4 h;
  h.h[0] = (f16)v.x; h.h[1] = (f16)v.y; h.h[2] = (f16)v.z; h.h[3] = (f16)v.w;
  *(uint2*)(solh + (size_t)row * 256 + k) = h.u;
}

__global__ __launch_bounds__(256) void k_cvt4(const float* __restrict__ in, f16* __restrict__ out, int n4) {
  int i = blockIdx.x * 256 + threadIdx.x;
  if (i < n4) {
    float4 v = *(const float4*)(in + (size_t)i * 4);
    H4 h;
    h.h[0] = (f16)v.x; h.h[1] = (f16)v.y; h.h[2] = (f16)v.z; h.h[3] = (f16)v.w;
    *(uint2*)(out + (size_t)i * 4) = h.u;
  }
}

// ---------------- weight fusion ----------------
__global__ __launch_bounds__(256) void k_fuse_wh(const float* __restrict__ fc_w, const float* __restrict__ ofc_w,
                                                 f16* __restrict__ fwh) {
  int r = blockIdx.x;        // 0..255 = h*64+o
  int d = threadIdx.x;       // 0..255
  int h = r >> 6, o = r & 63;
  float acc = 0.f;
  for (int f = 0; f < 64; ++f)
    acc = fmaf(ofc_w[(o << 6) + f], fc_w[(((h << 6) + f) << 8) + d], acc);
  fwh[(r << 8) + d] = (f16)acc;
}

__global__ __launch_bounds__(256) void k_fuse_attn(const float* __restrict__ fc_w,
                                                   const float* __restrict__ al, const float* __restrict__ ar,
                                                   float* __restrict__ alf) {
  int r = blockIdx.x;        // 0..7
  int d = threadIdx.x;
  int h = r & 3;
  const float* a = (r < 4) ? al : ar;
  float acc = 0.f;
  for (int f = 0; f < 64; ++f)
    acc = fmaf(a[(h << 6) + f], fc_w[(((h << 6) + f) << 8) + d], acc);
  alf[(r << 8) + d] = acc;
}

// ---------------- MFMA fp16 GEMM ----------------
// PERM=0: out[ra][col] fp32/fp16 per OUTH. PERM=2: featW_t[(b*4+h)][n][o] fp16.
template<int PERM, int OUTH>
__global__ __launch_bounds__(256) void k_gemm_f16(
    const f16* __restrict__ A, int lda, int K,
    const f16* __restrict__ W,
    const float* __restrict__ bias,
    void* __restrict__ outp, int ldo)
{
  __shared__ __align__(16) f16 As[64 * 32];
  __shared__ __align__(16) f16 Bs[128 * 32];
  const int tid = threadIdx.x;
  const int lane = tid & 63;
  const int w = tid >> 6;
  const int wr = w >> 1, wc = w & 1;
  const int ra0 = blockIdx.x * 64;
  const int c0 = blockIdx.y * 128;
  const int l2 = lane >> 2;
  const int lk8 = (lane & 3) * 8;

  f32x4 acc[2][4];
#pragma unroll
  for (int mr = 0; mr < 2; ++mr)
#pragma unroll
    for (int nr = 0; nr < 4; ++nr) acc[mr][nr] = (f32x4)0.f;

  const int fr = lane & 15;
  const int fg = (lane >> 4) * 8;

  for (int k0 = 0; k0 < K; k0 += 32) {
    gload_lds16(A + (size_t)(ra0 + 16 * w + l2) * lda + k0 + lk8, As + w * 512);
    gload_lds16(W + (size_t)(c0 + 32 * w + l2) * K + k0 + lk8, Bs + w * 1024);
    gload_lds16(W + (size_t)(c0 + 32 * w + 16 + l2) * K + k0 + lk8, Bs + w * 1024 + 512);
    __syncthreads();

    half8 af[2], bf[4];
#pragma unroll
    for (int mr = 0; mr < 2; ++mr)
      af[mr] = *(const half8*)(As + (wr * 32 + mr * 16 + fr) * 32 + fg);
#pragma unroll
    for (int nr = 0; nr < 4; ++nr)
      bf[nr] = *(const half8*)(Bs + (wc * 64 + nr * 16 + fr) * 32 + fg);
#pragma unroll
    for (int mr = 0; mr < 2; ++mr)
#pragma unroll
      for (int nr = 0; nr < 4; ++nr)
        acc[mr][nr] = __builtin_amdgcn_mfma_f32_16x16x32_f16(af[mr], bf[nr], acc[mr][nr], 0, 0, 0);
    __syncthreads();
  }

  const int r0 = (lane >> 4) * 4;
#pragma unroll
  for (int nr = 0; nr < 4; ++nr) {
    int col = c0 + wc * 64 + nr * 16 + fr;
    float bv = bias ? bias[col] : 0.f;
    int h = col >> 6, o = col & 63;
#pragma unroll
    for (int mr = 0; mr < 2; ++mr) {
      f32x4 v = acc[mr][nr];
#pragma unroll
      for (int r = 0; r < 4; ++r) {
        int ra = ra0 + wr * 32 + mr * 16 + r0 + r;
        float val = v[r] + bv;
        if (PERM == 2) {
          int n = ra % NN, b = ra / NN;
          ((f16*)outp)[(((size_t)(b * 4 + h) * NN + n) << 6) + o] = (f16)val;
        } else if (OUTH) {
          ((f16*)outp)[(size_t)ra * ldo + col] = (f16)val;
        } else {
          ((float*)outp)[(size_t)ra * ldo + col] = val;
        }
      }
    }
  }
}

// ---------------- el/er (bh-major transposed out) ----------------
__global__ __launch_bounds__(256) void k_eler3h(
    const f16* __restrict__ xh, int lda,
    const float* __restrict__ alf, float* __restrict__ el_t, float* __restrict__ er_t)
{
  int wid = threadIdx.x >> 6, lane = threadIdx.x & 63;
  int ra = blockIdx.x * 4 + wid;        // b*NN+n
  int k0 = lane << 2;
  H4 hv;
  hv.u = *(const uint2*)(xh + (size_t)ra * lda + k0);
  float x0 = (float)hv.h[0], x1 = (float)hv.h[1], x2 = (float)hv.h[2], x3 = (float)hv.h[3];
  int n = ra % NN, b = ra / NN;
#pragma unroll
  for (int oi = 0; oi < 8; ++oi) {
    float4 av = *(const float4*)(alf + (oi << 8) + k0);
    float s = x0 * av.x + x1 * av.y + x2 * av.z + x3 * av.w;
#pragma unroll
    for (int k = 32; k; k >>= 1) s += __shfl_xor(s, k);
    if (lane == 0) {
      int h = oi & 3;
      size_t idx = (size_t)(b * 4 + h) * NN + n;
      if (oi < 4) el_t[idx] = s;
      else        er_t[idx] = s;
    }
  }
}

// ---------------- edge softmax + aggregate, bh-split, wave-per-node ----------------
// blockIdx.x = chunk*16 + bh -> XCD = bid%8 = bh%8: per-XCD L2 keeps 2 bh slices hot.
// Aggregate: lane = es*16+cg; es = edge slot (4-way edge ILP), cg = 4-channel group (uint2 loads).
__global__ __launch_bounds__(256) void k_edge4(
    const f16* __restrict__ featW_t, const float* __restrict__ el_t, const float* __restrict__ er_t,
    const int* __restrict__ csr_src, const float* __restrict__ csr_w, const int* __restrict__ offs,
    const float* __restrict__ b2, f16* __restrict__ outh)
{
  __shared__ float2 as_[4][64];        // {alpha, bitcast(src)} per wave
  const int t = threadIdx.x;
  const int w = t >> 6, lane = t & 63;
  const int bh = blockIdx.x & 15;
  const int n = (blockIdx.x >> 4) * 4 + w;
  const int s0 = offs[n], s1 = offs[n + 1];
  const float erv = er_t[(size_t)bh * NN + n];
  const float* elp = el_t + (size_t)bh * NN;
  const f16* fW = featW_t + ((size_t)bh * NN << 6);
  const int es = lane >> 4;            // 0..3 edge slot
  const int cg = lane & 15;            // 0..15 channel group (4 ch)

  float m = -INFINITY, srun = 0.f;
  float a0 = 0.f, a1 = 0.f, a2 = 0.f, a3 = 0.f;

  for (int c0 = s0; c0 < s1; c0 += 64) {
    const int csz = min(64, s1 - c0);
    // ---- score phase: lane = edge ----
    float sc = -INFINITY;
    int src = 0;
    if (lane < csz) {
      src = csr_src[c0 + lane];
      float x = elp[src] + erv;
      x = (x > 0.f) ? x : 0.1f * x;
      sc = x * csr_w[c0 + lane];
    }
    float mc = sc;
#pragma unroll
    for (int k = 32; k; k >>= 1) mc = fmaxf(mc, __shfl_xor(mc, k));
    float mn = fmaxf(m, mc);
    float alpha = (lane < csz) ? __expf(sc - mn) : 0.f;   // 0-fill all 64 slots
    float ps = alpha;
#pragma unroll
    for (int k = 32; k; k >>= 1) ps += __shfl_xor(ps, k);
    float sl = (m == -INFINITY) ? 0.f : __expf(m - mn);
    srun = srun * sl + ps;
    m = mn;
    as_[w][lane] = make_float2(alpha, __int_as_float(src));
    // ---- aggregate: 4 edge slots x 16 channel groups ----
    a0 *= sl; a1 *= sl; a2 *= sl; a3 *= sl;
    for (int e = 0; e < csz; e += 4) {
      float2 pp = as_[w][e + es];          // broadcast within each 16-lane group
      int sn = __float_as_int(pp.y);
      H4 fv;
      fv.u = *(const uint2*)(fW + ((size_t)sn << 6) + (cg << 2));
      float al = pp.x;
      a0 = fmaf(al, (float)fv.h[0], a0);
      a1 = fmaf(al, (float)fv.h[1], a1);
      a2 = fmaf(al, (float)fv.h[2], a2);
      a3 = fmaf(al, (float)fv.h[3], a3);
    }
  }
  // cross-edge-slot reduction (es bits = lane bits 4,5)
#pragma unroll
  for (int k = 16; k <= 32; k <<= 1) {
    a0 += __shfl_xor(a0, k);
    a1 += __shfl_xor(a1, k);
    a2 += __shfl_xor(a2, k);
    a3 += __shfl_xor(a3, k);
  }
  if (lane < 16) {
    float invs = (s1 > s0) ? 1.f / srun : 0.f;
    const float4 bv = *(const float4*)(b2 + (cg << 2));
    H4 o;
    o.h[0] = (f16)fmaxf(fmaf(a0, invs, bv.x), 0.f);
    o.h[1] = (f16)fmaxf(fmaf(a1, invs, bv.y), 0.f);
    o.h[2] = (f16)fmaxf(fmaf(a2, invs, bv.z), 0.f);
    o.h[3] = (f16)fmaxf(fmaf(a3, invs, bv.w), 0.f);
    const int b = bh >> 2, h = bh & 3;
    *(uint2*)(outh + (((size_t)b * NN + n) << 9) + (h << 6) + (cg << 2)) = o.u;
  }
}

// ---------------- launch ----------------
extern "C" void kernel_launch(void* const* d_in, const int* in_sizes, int n_in,
                              void* d_out, int out_size, void* d_ws, size_t ws_size,
                              hipStream_t stream) {
  const float* sol    = (const float*)d_in[0];
  const float* w      = (const float*)d_in[1];
  const float* fc_w   = (const float*)d_in[2];
  const float* attn_l = (const float*)d_in[3];
  const float* attn_r = (const float*)d_in[4];
  const float* ofc_w  = (const float*)d_in[5];
  const float* ofc_b  = (const float*)d_in[6];
  const float* mlp_w  = (const float*)d_in[7];
  const float* mlp_b  = (const float*)d_in[8];
  const int*   d_src  = (const int*)d_in[9];
  const int*   d_dst  = (const int*)d_in[10];
  float* out = (float*)d_out;

  char* p = (char*)d_ws;
  auto alloc = [&](size_t bytes) { char* r = p; p += (bytes + 255) & ~(size_t)255; return r; };
  f16*   solh    = (f16*)alloc((size_t)NM * 256 * 2);
  f16*   out01h  = (f16*)alloc((size_t)NM * 512 * 2);
  f16*   featWt  = (f16*)alloc((size_t)NT * 64 * 2);       // [16][NN][64]
  f16*   fwh     = (f16*)alloc((size_t)ND * ND * 2);
  f16*   mlph    = (f16*)alloc((size_t)ND * 512 * 2);
  float* el_t    = (float*)alloc((size_t)NT * 4);          // [16][NN]
  float* er_t    = (float*)alloc((size_t)NT * 4);
  float* alf     = (float*)alloc((size_t)8 * ND * 4);
  int*   deg     = (int*)alloc((size_t)(NN + 1) * 4);
  int*   offs    = (int*)alloc((size_t)(NN + 1) * 4);
  int*   cursor  = (int*)alloc((size_t)NN * 4);
  int*   csr_src = (int*)alloc((size_t)NE * 4);
  float* csr_w   = (float*)alloc((size_t)NE * 4);
  if ((size_t)(p - (char*)d_ws) > ws_size) return;

  hipMemsetAsync(deg, 0, (size_t)NN * 4, stream);
  hipMemsetAsync(cursor, 0, (size_t)NN * 4, stream);
  k_deg<<<NE / 256, 256, 0, stream>>>(d_dst, deg);
  k_scan<<<1, 1024, 0, stream>>>(deg, offs);
  k_scatter<<<NE / 256, 256, 0, stream>>>(d_src, d_dst, w, offs, cursor, csr_src, csr_w);

  k_cvt_sol<<<NM * 64 / 256, 256, 0, stream>>>(sol, solh);
  k_cvt4<<<(ND * 512 / 4 + 255) / 256, 256, 0, stream>>>(mlp_w, mlph, ND * 512 / 4);

  for (int l = 0; l < 2; ++l) {
    const float* fcl = fc_w + (size_t)l * ND * ND;
    k_fuse_wh<<<256, 256, 0, stream>>>(fcl, ofc_w + (size_t)l * 64 * 64, fwh);
    k_fuse_attn<<<8, 256, 0, stream>>>(fcl, attn_l + (size_t)l * NH * 64, attn_r + (size_t)l * NH * 64, alf);
    const f16* Ah = (l == 0) ? solh : out01h;
    int lda = (l == 0) ? 256 : 512;
    k_gemm_f16<2, 1><<<dim3(NM / 64, ND / 128), 256, 0, stream>>>(
        Ah, lda, 256, fwh, nullptr, featWt, 64);
    k_eler3h<<<NM / 4, 256, 0, stream>>>(Ah, lda, alf, el_t, er_t);
    k_edge4<<<(NN / 4) * 16, 256, 0, stream>>>(featWt, el_t, er_t, csr_src, csr_w, offs,
                                               ofc_b + (size_t)l * 64, out01h + (l == 0 ? 0 : 256));
  }

  k_gemm_f16<0, 0><<<dim3(NM / 64, ND / 128), 256, 0, stream>>>(
      out01h, 512, 512, mlph, mlp_b, out, 256);
}